// Round 1
// baseline (251.112 us; speedup 1.0000x reference)
//
#include <hip/hip_runtime.h>

typedef __bf16 bf16;
typedef __bf16 bf16x4 __attribute__((ext_vector_type(4)));
typedef __bf16 bf16x8 __attribute__((ext_vector_type(8)));
typedef float  f32x4  __attribute__((ext_vector_type(4)));

#define HH 256
#define WW 256
#define NB 2
#define NC 64
#define NS 65536
#define EX 258      // extended conv grid: real coords -1..256, stored +1
#define NHEAD 4
#define DH 16

// ws layout (bytes)
#define OFF_CEXT   0ul
#define OFF_KV     34080768ul            // 2*64*258*258*4
#define OFF_WPK    67635200ul            // + 2*64*65536*4
#define OFF_ACC    67708928ul            // + 36864*2
#define OFF_ATTN   67718144ul            // + 2304*4

// ---------------- K0: pack weights to A-frag layout + zero accums ----------
__global__ void k0_prep(const float* __restrict__ wgt, bf16* __restrict__ wpk,
                        float* __restrict__ accums) {
    int t = blockIdx.x * 256 + threadIdx.x;
    if (t < 9 * 2 * 4 * 64) {
        int L   = t & 63;
        int mtg = (t >> 6) & 3;
        int kc  = (t >> 8) & 1;
        int tap = t >> 9;
        int o  = mtg * 16 + (L & 15);
        int cb = kc * 32 + (L >> 4) * 8;
        bf16x8 vv;
        #pragma unroll
        for (int j = 0; j < 8; j++)
            vv[j] = (bf16)wgt[(o * 64 + (cb + j)) * 9 + tap];
        *(bf16x8*)(wpk + t * 8) = vv;
    }
    int z = t - 9 * 2 * 4 * 64;
    if (z >= 0 && z < 2304) accums[z] = 0.0f;   // dots(2048)+qss(128)+kss(128)
}

// ---------------- K1: regular 3x3 conv on extended grid via MFMA -----------
// block: 256 thr = 4 waves; tile = 64 out-ch x 4 rows x 64 cols.
// wave (mpair,npair) covers o in [mpair*32,+32) x pos in [npair*32,+32).
__global__ __launch_bounds__(256, 2) void k1_conv(const float* __restrict__ clone,
                                                  const bf16* __restrict__ wpk,
                                                  float* __restrict__ cext) {
    const int Xt = blockIdx.x;   // 0..4
    const int Yt = blockIdx.y;   // 0..64
    const int b  = blockIdx.z;
    const int t  = threadIdx.x;
    const int L  = t & 63;
    const int wv = t >> 6;
    const int mpair = wv >> 1;
    const int npair = wv & 1;

    __shared__ bf16 tile[6 * 66 * 72];   // [row][col][c pad 72] = 57 KB

    // preload weight A-fragments: [mt][tap][kc], 144 VGPRs
    bf16x8 afrag[2][9][2];
    #pragma unroll
    for (int mt = 0; mt < 2; mt++)
        #pragma unroll
        for (int tap = 0; tap < 9; tap++)
            #pragma unroll
            for (int kc = 0; kc < 2; kc++) {
                int idx = ((tap * 2 + kc) * 4 + (mpair * 2 + mt)) * 64 + L;
                afrag[mt][tap][kc] = *(const bf16x8*)(wpk + idx * 8);
            }

    // stage clone: rows Yt*4-2..+3 (6), cols Xt*64-2..+63 (66), 64 ch, zero-pad OOB
    {
        const int x  = t & 63;
        const int cq = t >> 6;
        for (int r = 0; r < 6; r++) {
            int y = Yt * 4 - 2 + r;
            bool yin = (y >= 0) && (y < HH);
            int xg = Xt * 64 - 1 + x;          // col = x+1
            bool xin = (xg >= 0) && (xg < WW);
            #pragma unroll
            for (int cc = 0; cc < 4; cc++) {
                int c0 = cq * 16 + cc * 4;
                bf16x4 vv;
                #pragma unroll
                for (int i = 0; i < 4; i++) {
                    float f = (yin && xin) ? clone[((b * NC + c0 + i) * HH + y) * WW + xg] : 0.0f;
                    vv[i] = (bf16)f;
                }
                *(bf16x4*)(tile + (r * 66 + (x + 1)) * 72 + c0) = vv;
            }
            if (cq < 2) {                       // tail cols 0 and 65, lane = channel
                int col = cq ? 65 : 0;
                int xg2 = Xt * 64 - 2 + col;
                float f = (yin && xg2 >= 0 && xg2 < WW)
                          ? clone[((b * NC + x) * HH + y) * WW + xg2] : 0.0f;
                tile[(r * 66 + col) * 72 + x] = (bf16)f;
            }
        }
    }
    __syncthreads();

    const f32x4 zero4 = {0.0f, 0.0f, 0.0f, 0.0f};
    for (int Yi = 0; Yi < 4; Yi++) {
        f32x4 acc[2][2];
        acc[0][0] = zero4; acc[0][1] = zero4; acc[1][0] = zero4; acc[1][1] = zero4;
        #pragma unroll
        for (int tap = 0; tap < 9; tap++) {
            const int ky = tap / 3 - 1;
            const int kx = tap % 3 - 1;
            const int r = Yi + 1 + ky;
            #pragma unroll
            for (int kc = 0; kc < 2; kc++) {
                const int cb = kc * 32 + (L >> 4) * 8;
                #pragma unroll
                for (int nt = 0; nt < 2; nt++) {
                    const int col = npair * 32 + nt * 16 + (L & 15) + kx + 1;
                    bf16x8 bfrag = *(const bf16x8*)(tile + (r * 66 + col) * 72 + cb);
                    #pragma unroll
                    for (int mt = 0; mt < 2; mt++)
                        acc[mt][nt] = __builtin_amdgcn_mfma_f32_16x16x32_bf16(
                            afrag[mt][tap][kc], bfrag, acc[mt][nt], 0, 0, 0);
                }
            }
        }
        int Yp = Yt * 4 + Yi;
        if (Yp < EX) {
            #pragma unroll
            for (int mt = 0; mt < 2; mt++)
                #pragma unroll
                for (int nt = 0; nt < 2; nt++) {
                    int Xp = Xt * 64 + npair * 32 + nt * 16 + (L & 15);
                    if (Xp < EX) {
                        int o = mpair * 32 + mt * 16 + (L >> 4) * 4;  // D row=(lane>>4)*4+reg
                        f32x4 a = acc[mt][nt];
                        #pragma unroll
                        for (int rg = 0; rg < 4; rg++)
                            cext[((b * NC + o + rg) * EX + Yp) * EX + Xp] = a[rg];
                    }
                }
        }
    }
}

// ---------------- K2: 4-corner bilinear gather of conv output --------------
__global__ void k2_gather(const float* __restrict__ uu, const float* __restrict__ vv,
                          const float* __restrict__ cext, float* __restrict__ kv) {
    int idx = blockIdx.x * 256 + threadIdx.x;   // 131072 = B*H*W
    int b  = idx >> 16;
    int hw = idx & 65535;
    int hy = hw >> 8;
    int wx = hw & 255;
    float fv = vv[idx];
    float fu = uu[idx];
    float py = (float)hy + fv;
    float px = (float)wx + fu;
    float fy = floorf(py);
    float fx = floorf(px);
    float ay = py - fy;
    float ax = px - fx;
    int ys = (int)fy + 1;    // storage coords on EX grid
    int xs = (int)fx + 1;
    float w00 = (1.0f - ay) * (1.0f - ax);
    float w01 = (1.0f - ay) * ax;
    float w10 = ay * (1.0f - ax);
    float w11 = ay * ax;
    bool y0i = (ys >= 0) && (ys < EX);
    bool y1i = (ys + 1 >= 0) && (ys + 1 < EX);
    bool x0i = (xs >= 0) && (xs < EX);
    bool x1i = (xs + 1 >= 0) && (xs + 1 < EX);
    if (!y0i) { w00 = 0.0f; w01 = 0.0f; }
    if (!y1i) { w10 = 0.0f; w11 = 0.0f; }
    if (!x0i) { w00 = 0.0f; w10 = 0.0f; }
    if (!x1i) { w01 = 0.0f; w11 = 0.0f; }
    int y0c = ys < 0 ? 0 : (ys > EX - 1 ? EX - 1 : ys);
    int y1c = ys + 1 < 0 ? 0 : (ys + 1 > EX - 1 ? EX - 1 : ys + 1);
    int x0c = xs < 0 ? 0 : (xs > EX - 1 ? EX - 1 : xs);
    int x1c = xs + 1 < 0 ? 0 : (xs + 1 > EX - 1 ? EX - 1 : xs + 1);
    const float* base = cext + (size_t)b * NC * EX * EX;
    int i00 = y0c * EX + x0c;
    int i01 = y0c * EX + x1c;
    int i10 = y1c * EX + x0c;
    int i11 = y1c * EX + x1c;
    #pragma unroll 4
    for (int o = 0; o < NC; o++) {
        const float* p = base + o * (EX * EX);
        float val = w00 * p[i00] + w01 * p[i01] + w10 * p[i10] + w11 * p[i11];
        kv[((size_t)b * NC + o) * NS + hw] = val;
    }
}

// ---------------- K3: fused q.kT dots + sumsq norms via MFMA ---------------
__global__ __launch_bounds__(256) void k3_dots(const float* __restrict__ x,
                                               const float* __restrict__ kv,
                                               float* __restrict__ dots,
                                               float* __restrict__ qss,
                                               float* __restrict__ kss) {
    const int ch = blockIdx.x;   // 64 chunks of 1024 along S
    const int h  = blockIdx.y;
    const int b  = blockIdx.z;
    const int t  = threadIdx.x;
    const int L  = t & 63;
    const int wv = t >> 6;
    const int row = L & 15;      // q-row for A lanes / k-row for B lanes
    const int kg  = L >> 4;
    const float* qb = x  + ((size_t)(b * NC + h * DH + row)) * NS;
    const float* kb = kv + ((size_t)(b * NC + h * DH + row)) * NS;
    f32x4 acc = {0.0f, 0.0f, 0.0f, 0.0f};
    float qp = 0.0f, kp = 0.0f;
    const int s0 = ch * 1024 + wv * 256 + kg * 8;
    for (int it = 0; it < 8; it++) {
        int s = s0 + it * 32;
        f32x4 q0 = *(const f32x4*)(qb + s);
        f32x4 q1 = *(const f32x4*)(qb + s + 4);
        f32x4 k0 = *(const f32x4*)(kb + s);
        f32x4 k1 = *(const f32x4*)(kb + s + 4);
        bf16x8 qa, ka;
        #pragma unroll
        for (int j = 0; j < 4; j++) {
            qa[j]     = (bf16)q0[j];
            qa[j + 4] = (bf16)q1[j];
            ka[j]     = (bf16)k0[j];
            ka[j + 4] = (bf16)k1[j];
        }
        qp += q0[0]*q0[0] + q0[1]*q0[1] + q0[2]*q0[2] + q0[3]*q0[3]
            + q1[0]*q1[0] + q1[1]*q1[1] + q1[2]*q1[2] + q1[3]*q1[3];
        kp += k0[0]*k0[0] + k0[1]*k0[1] + k0[2]*k0[2] + k0[3]*k0[3]
            + k1[0]*k1[0] + k1[1]*k1[1] + k1[2]*k1[2] + k1[3]*k1[3];
        acc = __builtin_amdgcn_mfma_f32_16x16x32_bf16(qa, ka, acc, 0, 0, 0);
    }
    __shared__ float ldsD[256];
    __shared__ float ldsQ[16];
    __shared__ float ldsK[16];
    ldsD[t] = 0.0f;
    if (t < 16) { ldsQ[t] = 0.0f; ldsK[t] = 0.0f; }
    __syncthreads();
    #pragma unroll
    for (int rg = 0; rg < 4; rg++)
        atomicAdd(&ldsD[(kg * 4 + rg) * 16 + row], acc[rg]);  // D[i=kg*4+rg][j=lane&15]
    atomicAdd(&ldsQ[row], qp);
    atomicAdd(&ldsK[row], kp);
    __syncthreads();
    const int bh = b * NHEAD + h;
    atomicAdd(&dots[bh * 256 + t], ldsD[t]);
    if (t < 16) {
        atomicAdd(&qss[bh * 16 + t], ldsQ[t]);
        atomicAdd(&kss[bh * 16 + t], ldsK[t]);
    }
}

// ---------------- K4: normalize + temperature + softmax --------------------
__global__ void k4_attn(const float* __restrict__ dots, const float* __restrict__ qss,
                        const float* __restrict__ kss, const float* __restrict__ temp,
                        float* __restrict__ attn) {
    int bh = blockIdx.x;        // 0..7
    int h = bh & 3;
    int t = threadIdx.x;        // 256
    int i = t >> 4;
    int j = t & 15;
    __shared__ float l[256];
    float qn = fmaxf(sqrtf(qss[bh * 16 + i]), 1e-12f);
    float kn = fmaxf(sqrtf(kss[bh * 16 + j]), 1e-12f);
    float logit = dots[bh * 256 + t] / (qn * kn) * temp[h];
    l[t] = logit;
    __syncthreads();
    float mx = -1e30f;
    #pragma unroll
    for (int jj = 0; jj < 16; jj++) mx = fmaxf(mx, l[i * 16 + jj]);
    float sum = 0.0f;
    #pragma unroll
    for (int jj = 0; jj < 16; jj++) sum += expf(l[i * 16 + jj] - mx);
    attn[bh * 256 + t] = expf(logit - mx) / sum;
}

// ---------------- K5: out = attn @ kv --------------------------------------
__global__ __launch_bounds__(256) void k5_out(const float* __restrict__ kv,
                                              const float* __restrict__ attn,
                                              float* __restrict__ out) {
    const int ci = blockIdx.x;  // 0..63 (1024 s per block)
    const int h  = blockIdx.y;
    const int b  = blockIdx.z;
    const int t  = threadIdx.x;
    __shared__ float a[256];
    a[t] = attn[(b * NHEAD + h) * 256 + t];
    __syncthreads();
    const int s = (ci * 256 + t) * 4;
    const float* kvb = kv + ((size_t)(b * NC + h * DH)) * NS + s;
    f32x4 kvv[16];
    #pragma unroll
    for (int j = 0; j < 16; j++)
        kvv[j] = *(const f32x4*)(kvb + (size_t)j * NS);
    float* ob = out + ((size_t)(b * NC + h * DH)) * NS + s;
    #pragma unroll
    for (int i = 0; i < 16; i++) {
        f32x4 o = {0.0f, 0.0f, 0.0f, 0.0f};
        #pragma unroll
        for (int j = 0; j < 16; j++)
            o += a[i * 16 + j] * kvv[j];
        *(f32x4*)(ob + (size_t)i * NS) = o;
    }
}

extern "C" void kernel_launch(void* const* d_in, const int* in_sizes, int n_in,
                              void* d_out, int out_size, void* d_ws, size_t ws_size,
                              hipStream_t stream) {
    const float* clone = (const float*)d_in[0];
    const float* x     = (const float*)d_in[1];
    const float* u     = (const float*)d_in[2];
    const float* v     = (const float*)d_in[3];
    const float* wgt   = (const float*)d_in[4];
    const float* temp  = (const float*)d_in[5];
    float* out = (float*)d_out;

    char* ws = (char*)d_ws;
    float* cext   = (float*)(ws + OFF_CEXT);
    float* kv     = (float*)(ws + OFF_KV);
    bf16*  wpk    = (bf16*) (ws + OFF_WPK);
    float* accums = (float*)(ws + OFF_ACC);
    float* dots = accums;
    float* qss  = accums + 2048;
    float* kss  = accums + 2048 + 128;
    float* attn   = (float*)(ws + OFF_ATTN);

    k0_prep<<<28, 256, 0, stream>>>(wgt, wpk, accums);
    k1_conv<<<dim3(5, 65, 2), 256, 0, stream>>>(clone, wpk, cext);
    k2_gather<<<512, 256, 0, stream>>>(u, v, cext, kv);
    k3_dots<<<dim3(64, 4, 2), 256, 0, stream>>>(x, kv, dots, qss, kss);
    k4_attn<<<8, 256, 0, stream>>>(dots, qss, kss, temp, attn);
    k5_out<<<dim3(64, 4, 2), 256, 0, stream>>>(kv, attn, out);
}

// Round 2
// 205.418 us; speedup vs baseline: 1.2224x; 1.2224x over previous
//
#include <hip/hip_runtime.h>

typedef __bf16 bf16;
typedef __bf16 bf16x4 __attribute__((ext_vector_type(4)));
typedef __bf16 bf16x8 __attribute__((ext_vector_type(8)));
typedef float  f32x4  __attribute__((ext_vector_type(4)));

#define HH 256
#define WW 256
#define NB 2
#define NC 64
#define NS 65536
#define EX 258      // extended conv grid: real coords -1..256, stored +1
#define NHEAD 4
#define DH 16

// ws layout (bytes)
#define OFF_CLONET 0ul                 // 2*256*256*64*2 = 16777216
#define OFF_CEXT   16777216ul          // 2*258*258*64*2 = 17040384
#define OFF_KV     33817600ul          // 2*64*65536*2   = 16777216
#define OFF_WPK    50594816ul          // 73728
#define OFF_ACC    50668544ul          // 9216
#define OFF_ATTN   50677760ul          // 8192

// ---------------- K0: pack weights to A-frag layout + zero accums ----------
__global__ void k0_prep(const float* __restrict__ wgt, bf16* __restrict__ wpk,
                        float* __restrict__ accums) {
    int t = blockIdx.x * 256 + threadIdx.x;
    if (t < 9 * 2 * 4 * 64) {
        int L   = t & 63;
        int mtg = (t >> 6) & 3;
        int kc  = (t >> 8) & 1;
        int tap = t >> 9;
        int o  = mtg * 16 + (L & 15);
        int cb = kc * 32 + (L >> 4) * 8;
        bf16x8 vv;
        #pragma unroll
        for (int j = 0; j < 8; j++)
            vv[j] = (bf16)wgt[(o * 64 + (cb + j)) * 9 + tap];
        *(bf16x8*)(wpk + t * 8) = vv;
    }
    int z = t - 9 * 2 * 4 * 64;
    if (z >= 0 && z < 2304) accums[z] = 0.0f;   // dots(2048)+qss(128)+kss(128)
}

// ---------------- K0t: transpose clone [b][c][y][x] f32 -> [b][y][x][c] bf16
__global__ __launch_bounds__(256) void k0t(const float* __restrict__ clone,
                                           bf16* __restrict__ cloneT) {
    const int xc = blockIdx.x;   // 0..3  (64-x chunk)
    const int y  = blockIdx.y;   // 0..255
    const int b  = blockIdx.z;
    const int t  = threadIdx.x;
    __shared__ bf16 sm[64 * 68];          // [c][x], pitch 68

    {
        const int c = t >> 2, q = t & 3;
        const float* src = clone + ((size_t)(b * NC + c) * HH + y) * WW + xc * 64 + q * 16;
        #pragma unroll
        for (int i = 0; i < 4; i++) {
            f32x4 f = *(const f32x4*)(src + i * 4);
            bf16x4 h;
            #pragma unroll
            for (int j = 0; j < 4; j++) h[j] = (bf16)f[j];
            *(bf16x4*)(sm + c * 68 + q * 16 + i * 4) = h;
        }
    }
    __syncthreads();
    {
        const int x = t >> 2, cq = t & 3;
        bf16x8 o0, o1;
        #pragma unroll
        for (int j = 0; j < 8; j++) {
            o0[j] = sm[(cq * 16 + j) * 68 + x];
            o1[j] = sm[(cq * 16 + 8 + j) * 68 + x];
        }
        bf16* dst = cloneT + (((size_t)(b * HH + y) * WW + xc * 64 + x) << 6) + cq * 16;
        *(bf16x8*)(dst)     = o0;
        *(bf16x8*)(dst + 8) = o1;
    }
}

// ---------------- K1: regular 3x3 conv on extended grid via MFMA -----------
// block: 256 thr = 4 waves; tile = 64 out-ch x 4 rows x 64 cols.
__global__ __launch_bounds__(256, 2) void k1_conv(const bf16* __restrict__ cloneT,
                                                  const bf16* __restrict__ wpk,
                                                  bf16* __restrict__ cext) {
    const int Xt = blockIdx.x;   // 0..4
    const int Yt = blockIdx.y;   // 0..64
    const int b  = blockIdx.z;
    const int t  = threadIdx.x;
    const int L  = t & 63;
    const int wv = t >> 6;
    const int mpair = wv >> 1;
    const int npair = wv & 1;

    __shared__ bf16 tile[6 * 66 * 72];   // [row][col][c pad 72] = 57 KB

    // preload weight A-fragments: [mt][tap][kc]
    bf16x8 afrag[2][9][2];
    #pragma unroll
    for (int mt = 0; mt < 2; mt++)
        #pragma unroll
        for (int tap = 0; tap < 9; tap++)
            #pragma unroll
            for (int kc = 0; kc < 2; kc++) {
                int idx = ((tap * 2 + kc) * 4 + (mpair * 2 + mt)) * 64 + L;
                afrag[mt][tap][kc] = *(const bf16x8*)(wpk + idx * 8);
            }

    // stage: rows Yt*4-2..+3 (6), x = Xt*64-2..+63 (66 cols), 64 ch bf16.
    // cloneT is [y][x][c] so each 16B chunk (8 ch of one col) is contiguous
    // in BOTH global and LDS -> pure vector copy.
    for (int r = 0; r < 6; r++) {
        int y = Yt * 4 - 2 + r;
        bool yin = (y >= 0) && (y < HH);
        for (int j = t; j < 528; j += 256) {
            int col = j >> 3, ck = j & 7;
            int xg = Xt * 64 - 2 + col;
            bf16x8 val;
            if (yin && xg >= 0 && xg < WW) {
                val = *(const bf16x8*)(cloneT + (((size_t)(b * HH + y) * WW + xg) << 6) + ck * 8);
            } else {
                #pragma unroll
                for (int e = 0; e < 8; e++) val[e] = (bf16)0.0f;
            }
            *(bf16x8*)(tile + (r * 66 + col) * 72 + ck * 8) = val;
        }
    }
    __syncthreads();

    const f32x4 zero4 = {0.0f, 0.0f, 0.0f, 0.0f};
    for (int Yi = 0; Yi < 4; Yi++) {
        f32x4 acc[2][2];
        acc[0][0] = zero4; acc[0][1] = zero4; acc[1][0] = zero4; acc[1][1] = zero4;
        #pragma unroll
        for (int tap = 0; tap < 9; tap++) {
            const int ky = tap / 3 - 1;
            const int kx = tap % 3 - 1;
            const int r = Yi + 1 + ky;
            #pragma unroll
            for (int kc = 0; kc < 2; kc++) {
                const int cb = kc * 32 + (L >> 4) * 8;
                #pragma unroll
                for (int nt = 0; nt < 2; nt++) {
                    const int col = npair * 32 + nt * 16 + (L & 15) + kx + 1;
                    bf16x8 bfrag = *(const bf16x8*)(tile + (r * 66 + col) * 72 + cb);
                    #pragma unroll
                    for (int mt = 0; mt < 2; mt++)
                        acc[mt][nt] = __builtin_amdgcn_mfma_f32_16x16x32_bf16(
                            afrag[mt][tap][kc], bfrag, acc[mt][nt], 0, 0, 0);
                }
            }
        }
        int Yp = Yt * 4 + Yi;
        if (Yp < EX) {
            #pragma unroll
            for (int mt = 0; mt < 2; mt++)
                #pragma unroll
                for (int nt = 0; nt < 2; nt++) {
                    int Xp = Xt * 64 + npair * 32 + nt * 16 + (L & 15);
                    if (Xp < EX) {
                        int o = mpair * 32 + mt * 16 + (L >> 4) * 4;
                        bf16x4 st;
                        #pragma unroll
                        for (int rg = 0; rg < 4; rg++) st[rg] = (bf16)acc[mt][nt][rg];
                        // cext is [b][Yp][Xp][o] bf16
                        *(bf16x4*)(cext + ((((size_t)b * EX + Yp) * EX + Xp) << 6) + o) = st;
                    }
                }
        }
    }
}

// ---------------- K2: 4-corner bilinear gather of conv output --------------
__global__ __launch_bounds__(256) void k2_gather(const float* __restrict__ uu,
                                                 const float* __restrict__ vv,
                                                 const bf16* __restrict__ cext,
                                                 bf16* __restrict__ kv) {
    int gid = blockIdx.x * 256 + threadIdx.x;  // 262144
    int ckh = gid >> 17;                        // channel half (0/1)
    int idx = gid & 131071;                     // pixel
    int b  = idx >> 16;
    int hw = idx & 65535;
    int hy = hw >> 8;
    int wx = hw & 255;
    float fv = vv[idx];
    float fu = uu[idx];
    float py = (float)hy + fv;
    float px = (float)wx + fu;
    float fy = floorf(py);
    float fx = floorf(px);
    float ay = py - fy;
    float ax = px - fx;
    int ys = (int)fy + 1;    // storage coords on EX grid
    int xs = (int)fx + 1;
    float w00 = (1.0f - ay) * (1.0f - ax);
    float w01 = (1.0f - ay) * ax;
    float w10 = ay * (1.0f - ax);
    float w11 = ay * ax;
    bool y0i = (ys >= 0) && (ys < EX);
    bool y1i = (ys + 1 >= 0) && (ys + 1 < EX);
    bool x0i = (xs >= 0) && (xs < EX);
    bool x1i = (xs + 1 >= 0) && (xs + 1 < EX);
    if (!y0i) { w00 = 0.0f; w01 = 0.0f; }
    if (!y1i) { w10 = 0.0f; w11 = 0.0f; }
    if (!x0i) { w00 = 0.0f; w10 = 0.0f; }
    if (!x1i) { w01 = 0.0f; w11 = 0.0f; }
    int y0c = ys < 0 ? 0 : (ys > EX - 1 ? EX - 1 : ys);
    int y1c = ys + 1 < 0 ? 0 : (ys + 1 > EX - 1 ? EX - 1 : ys + 1);
    int x0c = xs < 0 ? 0 : (xs > EX - 1 ? EX - 1 : xs);
    int x1c = xs + 1 < 0 ? 0 : (xs + 1 > EX - 1 ? EX - 1 : xs + 1);
    const bf16* pb = cext + (((size_t)b * EX * EX) << 6);
    size_t i00 = ((size_t)(y0c * EX + x0c)) << 6;
    size_t i01 = ((size_t)(y0c * EX + x1c)) << 6;
    size_t i10 = ((size_t)(y1c * EX + x0c)) << 6;
    size_t i11 = ((size_t)(y1c * EX + x1c)) << 6;
    bf16* kvp = kv + (((size_t)(b * NC + ckh * 32)) << 16) + hw;
    #pragma unroll
    for (int ck = 0; ck < 4; ck++) {
        int c0 = ckh * 32 + ck * 8;
        bf16x8 c00 = *(const bf16x8*)(pb + i00 + c0);
        bf16x8 c01 = *(const bf16x8*)(pb + i01 + c0);
        bf16x8 c10 = *(const bf16x8*)(pb + i10 + c0);
        bf16x8 c11 = *(const bf16x8*)(pb + i11 + c0);
        #pragma unroll
        for (int j = 0; j < 8; j++) {
            float val = w00 * (float)c00[j] + w01 * (float)c01[j]
                      + w10 * (float)c10[j] + w11 * (float)c11[j];
            kvp[((size_t)(ck * 8 + j)) << 16] = (bf16)val;
        }
    }
}

// ---------------- K3: fused q.kT dots + sumsq norms via MFMA ---------------
__global__ __launch_bounds__(256) void k3_dots(const float* __restrict__ x,
                                               const bf16* __restrict__ kv,
                                               float* __restrict__ dots,
                                               float* __restrict__ qss,
                                               float* __restrict__ kss) {
    const int ch = blockIdx.x;   // 64 chunks of 1024 along S
    const int h  = blockIdx.y;
    const int b  = blockIdx.z;
    const int t  = threadIdx.x;
    const int L  = t & 63;
    const int wv = t >> 6;
    const int row = L & 15;
    const int kg  = L >> 4;
    const float* qb = x + ((size_t)(b * NC + h * DH + row)) * NS;
    const bf16*  kb = kv + (((size_t)(b * NC + h * DH + row)) << 16);
    f32x4 acc = {0.0f, 0.0f, 0.0f, 0.0f};
    float qp = 0.0f, kp = 0.0f;
    const int s0 = ch * 1024 + wv * 256 + kg * 8;
    for (int it = 0; it < 8; it++) {
        int s = s0 + it * 32;
        f32x4 q0 = *(const f32x4*)(qb + s);
        f32x4 q1 = *(const f32x4*)(qb + s + 4);
        bf16x8 ka = *(const bf16x8*)(kb + s);
        bf16x8 qa;
        #pragma unroll
        for (int j = 0; j < 4; j++) {
            qa[j]     = (bf16)q0[j];
            qa[j + 4] = (bf16)q1[j];
        }
        qp += q0[0]*q0[0] + q0[1]*q0[1] + q0[2]*q0[2] + q0[3]*q0[3]
            + q1[0]*q1[0] + q1[1]*q1[1] + q1[2]*q1[2] + q1[3]*q1[3];
        #pragma unroll
        for (int j = 0; j < 8; j++) {
            float kf = (float)ka[j];
            kp += kf * kf;
        }
        acc = __builtin_amdgcn_mfma_f32_16x16x32_bf16(qa, ka, acc, 0, 0, 0);
    }
    __shared__ float ldsD[256];
    __shared__ float ldsQ[16];
    __shared__ float ldsK[16];
    ldsD[t] = 0.0f;
    if (t < 16) { ldsQ[t] = 0.0f; ldsK[t] = 0.0f; }
    __syncthreads();
    #pragma unroll
    for (int rg = 0; rg < 4; rg++)
        atomicAdd(&ldsD[(kg * 4 + rg) * 16 + row], acc[rg]);
    atomicAdd(&ldsQ[row], qp);
    atomicAdd(&ldsK[row], kp);
    __syncthreads();
    const int bh = b * NHEAD + h;
    atomicAdd(&dots[bh * 256 + t], ldsD[t]);
    if (t < 16) {
        atomicAdd(&qss[bh * 16 + t], ldsQ[t]);
        atomicAdd(&kss[bh * 16 + t], ldsK[t]);
    }
}

// ---------------- K4: normalize + temperature + softmax --------------------
__global__ void k4_attn(const float* __restrict__ dots, const float* __restrict__ qss,
                        const float* __restrict__ kss, const float* __restrict__ temp,
                        float* __restrict__ attn) {
    int bh = blockIdx.x;        // 0..7
    int h = bh & 3;
    int t = threadIdx.x;        // 256
    int i = t >> 4;
    int j = t & 15;
    __shared__ float l[256];
    float qn = fmaxf(sqrtf(qss[bh * 16 + i]), 1e-12f);
    float kn = fmaxf(sqrtf(kss[bh * 16 + j]), 1e-12f);
    float logit = dots[bh * 256 + t] / (qn * kn) * temp[h];
    l[t] = logit;
    __syncthreads();
    float mx = -1e30f;
    #pragma unroll
    for (int jj = 0; jj < 16; jj++) mx = fmaxf(mx, l[i * 16 + jj]);
    float sum = 0.0f;
    #pragma unroll
    for (int jj = 0; jj < 16; jj++) sum += expf(l[i * 16 + jj] - mx);
    attn[bh * 256 + t] = expf(logit - mx) / sum;
}

// ---------------- K5: out = attn @ kv --------------------------------------
__global__ __launch_bounds__(256) void k5_out(const bf16* __restrict__ kv,
                                              const float* __restrict__ attn,
                                              float* __restrict__ out) {
    const int ci = blockIdx.x;  // 0..63 (1024 s per block)
    const int h  = blockIdx.y;
    const int b  = blockIdx.z;
    const int t  = threadIdx.x;
    __shared__ float a[256];
    a[t] = attn[(b * NHEAD + h) * 256 + t];
    __syncthreads();
    const int s = (ci * 256 + t) * 4;
    const bf16* kvb = kv + (((size_t)(b * NC + h * DH)) << 16) + s;
    f32x4 kf[16];
    #pragma unroll
    for (int j = 0; j < 16; j++) {
        bf16x4 kk = *(const bf16x4*)(kvb + ((size_t)j << 16));
        #pragma unroll
        for (int e = 0; e < 4; e++) kf[j][e] = (float)kk[e];
    }
    float* ob = out + ((size_t)(b * NC + h * DH)) * NS + s;
    #pragma unroll
    for (int i = 0; i < 16; i++) {
        f32x4 o = {0.0f, 0.0f, 0.0f, 0.0f};
        #pragma unroll
        for (int j = 0; j < 16; j++)
            o += a[i * 16 + j] * kf[j];
        *(f32x4*)(ob + (size_t)i * NS) = o;
    }
}

extern "C" void kernel_launch(void* const* d_in, const int* in_sizes, int n_in,
                              void* d_out, int out_size, void* d_ws, size_t ws_size,
                              hipStream_t stream) {
    const float* clone = (const float*)d_in[0];
    const float* x     = (const float*)d_in[1];
    const float* u     = (const float*)d_in[2];
    const float* v     = (const float*)d_in[3];
    const float* wgt   = (const float*)d_in[4];
    const float* temp  = (const float*)d_in[5];
    float* out = (float*)d_out;

    char* ws = (char*)d_ws;
    bf16*  cloneT = (bf16*) (ws + OFF_CLONET);
    bf16*  cext   = (bf16*) (ws + OFF_CEXT);
    bf16*  kv     = (bf16*) (ws + OFF_KV);
    bf16*  wpk    = (bf16*) (ws + OFF_WPK);
    float* accums = (float*)(ws + OFF_ACC);
    float* dots = accums;
    float* qss  = accums + 2048;
    float* kss  = accums + 2048 + 128;
    float* attn   = (float*)(ws + OFF_ATTN);

    k0_prep<<<28, 256, 0, stream>>>(wgt, wpk, accums);
    k0t<<<dim3(4, 256, 2), 256, 0, stream>>>(clone, cloneT);
    k1_conv<<<dim3(5, 65, 2), 256, 0, stream>>>(cloneT, wpk, cext);
    k2_gather<<<1024, 256, 0, stream>>>(u, v, cext, kv);
    k3_dots<<<dim3(64, 4, 2), 256, 0, stream>>>(x, kv, dots, qss, kss);
    k4_attn<<<8, 256, 0, stream>>>(dots, qss, kss, temp, attn);
    k5_out<<<dim3(64, 4, 2), 256, 0, stream>>>(kv, attn, out);
}

// Round 3
// 184.727 us; speedup vs baseline: 1.3594x; 1.1120x over previous
//
#include <hip/hip_runtime.h>

typedef __bf16 bf16;
typedef __bf16 bf16x4 __attribute__((ext_vector_type(4)));
typedef __bf16 bf16x8 __attribute__((ext_vector_type(8)));
typedef float  f32x4  __attribute__((ext_vector_type(4)));

#define HH 256
#define WW 256
#define NB 2
#define NC 64
#define NS 65536
#define EX 258      // extended conv grid: real coords -1..256, stored +1
#define NHEAD 4
#define DH 16

// ws layout (bytes)
#define OFF_CLONET 0ul                 // 2*256*256*64*2 = 16777216
#define OFF_CEXT   16777216ul          // 2*258*258*64*2 = 17040384
#define OFF_KV     33817600ul          // 2*64*65536*2   = 16777216
#define OFF_WPK    50594816ul          // 73728
#define OFF_ACC    50668544ul          // 9216

// ---------------- K0t: transpose clone [b][c][y][x] f32 -> [b][y][x][c] bf16
//                  + (aux blocks) pack weights to A-frag layout, zero accums
__global__ __launch_bounds__(256) void k0t(const float* __restrict__ clone,
                                           bf16* __restrict__ cloneT,
                                           const float* __restrict__ wgt,
                                           bf16* __restrict__ wpk,
                                           float* __restrict__ accums) {
    const int xc = blockIdx.x;   // 0..3  (64-x chunk)
    const int y  = blockIdx.y;   // 0..255
    const int b  = blockIdx.z;
    const int t  = threadIdx.x;

    // ---- aux: weight pack + accumulator zero (28 blocks' worth of work) ----
    if (b == 0 && y < 7) {
        int t2 = (y * 4 + xc) * 256 + t;     // 0..7167
        if (t2 < 9 * 2 * 4 * 64) {
            int L   = t2 & 63;
            int mtg = (t2 >> 6) & 3;
            int kc  = (t2 >> 8) & 1;
            int tap = t2 >> 9;
            int o  = mtg * 16 + (L & 15);
            int cb = kc * 32 + (L >> 4) * 8;
            bf16x8 vv;
            #pragma unroll
            for (int j = 0; j < 8; j++)
                vv[j] = (bf16)wgt[(o * 64 + (cb + j)) * 9 + tap];
            *(bf16x8*)(wpk + t2 * 8) = vv;
        }
        int z = t2 - 9 * 2 * 4 * 64;
        if (z >= 0 && z < 2304) accums[z] = 0.0f;   // dots(2048)+qss(128)+kss(128)
    }

    // ---- transpose ----
    __shared__ bf16 sm[64 * 68];          // [c][x], pitch 68
    {
        const int c = t >> 2, q = t & 3;
        const float* src = clone + ((size_t)(b * NC + c) * HH + y) * WW + xc * 64 + q * 16;
        #pragma unroll
        for (int i = 0; i < 4; i++) {
            f32x4 f = *(const f32x4*)(src + i * 4);
            bf16x4 h;
            #pragma unroll
            for (int j = 0; j < 4; j++) h[j] = (bf16)f[j];
            *(bf16x4*)(sm + c * 68 + q * 16 + i * 4) = h;
        }
    }
    __syncthreads();
    {
        const int x = t >> 2, cq = t & 3;
        bf16x8 o0, o1;
        #pragma unroll
        for (int j = 0; j < 8; j++) {
            o0[j] = sm[(cq * 16 + j) * 68 + x];
            o1[j] = sm[(cq * 16 + 8 + j) * 68 + x];
        }
        bf16* dst = cloneT + (((size_t)(b * HH + y) * WW + xc * 64 + x) << 6) + cq * 16;
        *(bf16x8*)(dst)     = o0;
        *(bf16x8*)(dst + 8) = o1;
    }
}

// ---------------- K1: regular 3x3 conv on extended grid via MFMA -----------
// block: 256 thr = 4 waves; tile = 64 out-ch x 6 rows x 64 cols.
// grid = 5 x 43 x 2 = 430 blocks, 2 blocks/CU -> single occupancy round.
// dynamic LDS = 8*66*72*2 = 76032 B (needs hipFuncSetAttribute).
__global__ __launch_bounds__(256, 2) void k1_conv(const bf16* __restrict__ cloneT,
                                                  const bf16* __restrict__ wpk,
                                                  bf16* __restrict__ cext) {
    const int Xt = blockIdx.x;   // 0..4
    const int Yt = blockIdx.y;   // 0..42  (43*6 = 258 exactly)
    const int b  = blockIdx.z;
    const int t  = threadIdx.x;
    const int L  = t & 63;
    const int wv = t >> 6;
    const int mpair = wv >> 1;
    const int npair = wv & 1;

    extern __shared__ bf16 tile[];       // [8 rows][66 cols][c pitch 72]

    // preload weight A-fragments: [mt][tap][kc]
    bf16x8 afrag[2][9][2];
    #pragma unroll
    for (int mt = 0; mt < 2; mt++)
        #pragma unroll
        for (int tap = 0; tap < 9; tap++)
            #pragma unroll
            for (int kc = 0; kc < 2; kc++) {
                int idx = ((tap * 2 + kc) * 4 + (mpair * 2 + mt)) * 64 + L;
                afrag[mt][tap][kc] = *(const bf16x8*)(wpk + idx * 8);
            }

    // stage: rows Yt*6-2..+5 (8), x = Xt*64-2..+63 (66 cols), 64 ch bf16.
    for (int r = 0; r < 8; r++) {
        int y = Yt * 6 - 2 + r;
        bool yin = (y >= 0) && (y < HH);
        for (int j = t; j < 528; j += 256) {
            int col = j >> 3, ck = j & 7;
            int xg = Xt * 64 - 2 + col;
            bf16x8 val;
            if (yin && xg >= 0 && xg < WW) {
                val = *(const bf16x8*)(cloneT + (((size_t)(b * HH + y) * WW + xg) << 6) + ck * 8);
            } else {
                #pragma unroll
                for (int e = 0; e < 8; e++) val[e] = (bf16)0.0f;
            }
            *(bf16x8*)(tile + (r * 66 + col) * 72 + ck * 8) = val;
        }
    }
    __syncthreads();

    const f32x4 zero4 = {0.0f, 0.0f, 0.0f, 0.0f};
    for (int Yi = 0; Yi < 6; Yi++) {
        f32x4 acc[2][2];
        acc[0][0] = zero4; acc[0][1] = zero4; acc[1][0] = zero4; acc[1][1] = zero4;
        #pragma unroll
        for (int tap = 0; tap < 9; tap++) {
            const int ky = tap / 3 - 1;
            const int kx = tap % 3 - 1;
            const int r = Yi + 1 + ky;
            #pragma unroll
            for (int kc = 0; kc < 2; kc++) {
                const int cb = kc * 32 + (L >> 4) * 8;
                #pragma unroll
                for (int nt = 0; nt < 2; nt++) {
                    const int col = npair * 32 + nt * 16 + (L & 15) + kx + 1;
                    bf16x8 bfrag = *(const bf16x8*)(tile + (r * 66 + col) * 72 + cb);
                    #pragma unroll
                    for (int mt = 0; mt < 2; mt++)
                        acc[mt][nt] = __builtin_amdgcn_mfma_f32_16x16x32_bf16(
                            afrag[mt][tap][kc], bfrag, acc[mt][nt], 0, 0, 0);
                }
            }
        }
        int Yp = Yt * 6 + Yi;    // always < 258
        #pragma unroll
        for (int mt = 0; mt < 2; mt++)
            #pragma unroll
            for (int nt = 0; nt < 2; nt++) {
                int Xp = Xt * 64 + npair * 32 + nt * 16 + (L & 15);
                if (Xp < EX) {
                    int o = mpair * 32 + mt * 16 + (L >> 4) * 4;
                    bf16x4 st;
                    #pragma unroll
                    for (int rg = 0; rg < 4; rg++) st[rg] = (bf16)acc[mt][nt][rg];
                    // cext is [b][Yp][Xp][o] bf16
                    *(bf16x4*)(cext + ((((size_t)b * EX + Yp) * EX + Xp) << 6) + o) = st;
                }
            }
    }
}

// ---------------- K2: 4-corner bilinear gather of conv output --------------
__global__ __launch_bounds__(256) void k2_gather(const float* __restrict__ uu,
                                                 const float* __restrict__ vv,
                                                 const bf16* __restrict__ cext,
                                                 bf16* __restrict__ kv) {
    int gid = blockIdx.x * 256 + threadIdx.x;  // 262144
    int ckh = gid >> 17;                        // channel half (0/1)
    int idx = gid & 131071;                     // pixel
    int b  = idx >> 16;
    int hw = idx & 65535;
    int hy = hw >> 8;
    int wx = hw & 255;
    float fv = vv[idx];
    float fu = uu[idx];
    float py = (float)hy + fv;
    float px = (float)wx + fu;
    float fy = floorf(py);
    float fx = floorf(px);
    float ay = py - fy;
    float ax = px - fx;
    int ys = (int)fy + 1;    // storage coords on EX grid
    int xs = (int)fx + 1;
    float w00 = (1.0f - ay) * (1.0f - ax);
    float w01 = (1.0f - ay) * ax;
    float w10 = ay * (1.0f - ax);
    float w11 = ay * ax;
    bool y0i = (ys >= 0) && (ys < EX);
    bool y1i = (ys + 1 >= 0) && (ys + 1 < EX);
    bool x0i = (xs >= 0) && (xs < EX);
    bool x1i = (xs + 1 >= 0) && (xs + 1 < EX);
    if (!y0i) { w00 = 0.0f; w01 = 0.0f; }
    if (!y1i) { w10 = 0.0f; w11 = 0.0f; }
    if (!x0i) { w00 = 0.0f; w10 = 0.0f; }
    if (!x1i) { w01 = 0.0f; w11 = 0.0f; }
    int y0c = ys < 0 ? 0 : (ys > EX - 1 ? EX - 1 : ys);
    int y1c = ys + 1 < 0 ? 0 : (ys + 1 > EX - 1 ? EX - 1 : ys + 1);
    int x0c = xs < 0 ? 0 : (xs > EX - 1 ? EX - 1 : xs);
    int x1c = xs + 1 < 0 ? 0 : (xs + 1 > EX - 1 ? EX - 1 : xs + 1);
    const bf16* pb = cext + (((size_t)b * EX * EX) << 6);
    size_t i00 = ((size_t)(y0c * EX + x0c)) << 6;
    size_t i01 = ((size_t)(y0c * EX + x1c)) << 6;
    size_t i10 = ((size_t)(y1c * EX + x0c)) << 6;
    size_t i11 = ((size_t)(y1c * EX + x1c)) << 6;
    bf16* kvp = kv + (((size_t)(b * NC + ckh * 32)) << 16) + hw;
    #pragma unroll
    for (int ck = 0; ck < 4; ck++) {
        int c0 = ckh * 32 + ck * 8;
        bf16x8 c00 = *(const bf16x8*)(pb + i00 + c0);
        bf16x8 c01 = *(const bf16x8*)(pb + i01 + c0);
        bf16x8 c10 = *(const bf16x8*)(pb + i10 + c0);
        bf16x8 c11 = *(const bf16x8*)(pb + i11 + c0);
        #pragma unroll
        for (int j = 0; j < 8; j++) {
            float val = w00 * (float)c00[j] + w01 * (float)c01[j]
                      + w10 * (float)c10[j] + w11 * (float)c11[j];
            kvp[((size_t)(ck * 8 + j)) << 16] = (bf16)val;
        }
    }
}

// ---------------- K3: fused q.kT dots + sumsq norms via MFMA ---------------
__global__ __launch_bounds__(256) void k3_dots(const float* __restrict__ x,
                                               const bf16* __restrict__ kv,
                                               float* __restrict__ dots,
                                               float* __restrict__ qss,
                                               float* __restrict__ kss) {
    const int ch = blockIdx.x;   // 64 chunks of 1024 along S
    const int h  = blockIdx.y;
    const int b  = blockIdx.z;
    const int t  = threadIdx.x;
    const int L  = t & 63;
    const int wv = t >> 6;
    const int row = L & 15;
    const int kg  = L >> 4;
    const float* qb = x + ((size_t)(b * NC + h * DH + row)) * NS;
    const bf16*  kb = kv + (((size_t)(b * NC + h * DH + row)) << 16);
    f32x4 acc = {0.0f, 0.0f, 0.0f, 0.0f};
    float qp = 0.0f, kp = 0.0f;
    const int s0 = ch * 1024 + wv * 256 + kg * 8;
    for (int it = 0; it < 8; it++) {
        int s = s0 + it * 32;
        f32x4 q0 = *(const f32x4*)(qb + s);
        f32x4 q1 = *(const f32x4*)(qb + s + 4);
        bf16x8 ka = *(const bf16x8*)(kb + s);
        bf16x8 qa;
        #pragma unroll
        for (int j = 0; j < 4; j++) {
            qa[j]     = (bf16)q0[j];
            qa[j + 4] = (bf16)q1[j];
        }
        qp += q0[0]*q0[0] + q0[1]*q0[1] + q0[2]*q0[2] + q0[3]*q0[3]
            + q1[0]*q1[0] + q1[1]*q1[1] + q1[2]*q1[2] + q1[3]*q1[3];
        #pragma unroll
        for (int j = 0; j < 8; j++) {
            float kf = (float)ka[j];
            kp += kf * kf;
        }
        acc = __builtin_amdgcn_mfma_f32_16x16x32_bf16(qa, ka, acc, 0, 0, 0);
    }
    __shared__ float ldsD[256];
    __shared__ float ldsQ[16];
    __shared__ float ldsK[16];
    ldsD[t] = 0.0f;
    if (t < 16) { ldsQ[t] = 0.0f; ldsK[t] = 0.0f; }
    __syncthreads();
    #pragma unroll
    for (int rg = 0; rg < 4; rg++)
        atomicAdd(&ldsD[(kg * 4 + rg) * 16 + row], acc[rg]);
    atomicAdd(&ldsQ[row], qp);
    atomicAdd(&ldsK[row], kp);
    __syncthreads();
    const int bh = b * NHEAD + h;
    atomicAdd(&dots[bh * 256 + t], ldsD[t]);
    if (t < 16) {
        atomicAdd(&qss[bh * 16 + t], ldsQ[t]);
        atomicAdd(&kss[bh * 16 + t], ldsK[t]);
    }
}

// ---------------- K5: softmax (redundant per block) + out = attn @ kv ------
__global__ __launch_bounds__(256) void k5_out(const bf16* __restrict__ kv,
                                              const float* __restrict__ dots,
                                              const float* __restrict__ qss,
                                              const float* __restrict__ kss,
                                              const float* __restrict__ temp,
                                              float* __restrict__ out) {
    const int ci = blockIdx.x;  // 0..63 (1024 s per block)
    const int h  = blockIdx.y;
    const int b  = blockIdx.z;
    const int t  = threadIdx.x;
    const int bh = b * NHEAD + h;
    __shared__ float l[256];
    __shared__ float a[256];
    {
        int i = t >> 4, j = t & 15;
        float qn = fmaxf(sqrtf(qss[bh * 16 + i]), 1e-12f);
        float kn = fmaxf(sqrtf(kss[bh * 16 + j]), 1e-12f);
        float logit = dots[bh * 256 + t] / (qn * kn) * temp[h];
        l[t] = logit;
        __syncthreads();
        float mx = -1e30f;
        #pragma unroll
        for (int jj = 0; jj < 16; jj++) mx = fmaxf(mx, l[i * 16 + jj]);
        float sum = 0.0f;
        #pragma unroll
        for (int jj = 0; jj < 16; jj++) sum += expf(l[i * 16 + jj] - mx);
        a[t] = expf(logit - mx) / sum;
        __syncthreads();
    }
    const int s = (ci * 256 + t) * 4;
    const bf16* kvb = kv + (((size_t)(b * NC + h * DH)) << 16) + s;
    f32x4 kf[16];
    #pragma unroll
    for (int j = 0; j < 16; j++) {
        bf16x4 kk = *(const bf16x4*)(kvb + ((size_t)j << 16));
        #pragma unroll
        for (int e = 0; e < 4; e++) kf[j][e] = (float)kk[e];
    }
    float* ob = out + ((size_t)(b * NC + h * DH)) * NS + s;
    #pragma unroll
    for (int i = 0; i < 16; i++) {
        f32x4 o = {0.0f, 0.0f, 0.0f, 0.0f};
        #pragma unroll
        for (int j = 0; j < 16; j++)
            o += a[i * 16 + j] * kf[j];
        *(f32x4*)(ob + (size_t)i * NS) = o;
    }
}

extern "C" void kernel_launch(void* const* d_in, const int* in_sizes, int n_in,
                              void* d_out, int out_size, void* d_ws, size_t ws_size,
                              hipStream_t stream) {
    const float* clone = (const float*)d_in[0];
    const float* x     = (const float*)d_in[1];
    const float* u     = (const float*)d_in[2];
    const float* v     = (const float*)d_in[3];
    const float* wgt   = (const float*)d_in[4];
    const float* temp  = (const float*)d_in[5];
    float* out = (float*)d_out;

    char* ws = (char*)d_ws;
    bf16*  cloneT = (bf16*) (ws + OFF_CLONET);
    bf16*  cext   = (bf16*) (ws + OFF_CEXT);
    bf16*  kv     = (bf16*) (ws + OFF_KV);
    bf16*  wpk    = (bf16*) (ws + OFF_WPK);
    float* accums = (float*)(ws + OFF_ACC);
    float* dots = accums;
    float* qss  = accums + 2048;
    float* kss  = accums + 2048 + 128;

    static bool attr_set = false;
    if (!attr_set) {
        hipFuncSetAttribute((const void*)k1_conv,
                            hipFuncAttributeMaxDynamicSharedMemorySize, 76032);
        attr_set = true;
    }

    k0t<<<dim3(4, 256, 2), 256, 0, stream>>>(clone, cloneT, wgt, wpk, accums);
    k1_conv<<<dim3(5, 43, 2), 256, 76032, stream>>>(cloneT, wpk, cext);
    k2_gather<<<1024, 256, 0, stream>>>(u, v, cext, kv);
    k3_dots<<<dim3(64, 4, 2), 256, 0, stream>>>(x, kv, dots, qss, kss);
    k5_out<<<dim3(64, 4, 2), 256, 0, stream>>>(kv, dots, qss, kss, temp, out);
}

// Round 4
// 172.532 us; speedup vs baseline: 1.4555x; 1.0707x over previous
//
#include <hip/hip_runtime.h>

typedef __bf16 bf16;
typedef __bf16 bf16x4 __attribute__((ext_vector_type(4)));
typedef __bf16 bf16x8 __attribute__((ext_vector_type(8)));
typedef float  f32x4  __attribute__((ext_vector_type(4)));

#define HH 256
#define WW 256
#define NB 2
#define NC 64
#define NS 65536
#define EX 258      // extended conv grid: real coords -1..256, stored +1
#define NHEAD 4
#define DH 16

// ws layout (bytes)
#define OFF_CEXT   0ul                 // 2*258*258*64*2 = 17040384
#define OFF_KV     17040384ul          // 2*64*65536*2   = 16777216
#define OFF_WPK    33817600ul          // 73728
#define OFF_ACC    33891328ul          // 9216

// ---------------- K0w: pack weights to A-frag layout + zero accums ---------
__global__ void k0w(const float* __restrict__ wgt, bf16* __restrict__ wpk,
                    float* __restrict__ accums) {
    int t = blockIdx.x * 256 + threadIdx.x;
    if (t < 9 * 2 * 4 * 64) {
        int L   = t & 63;
        int mtg = (t >> 6) & 3;
        int kc  = (t >> 8) & 1;
        int tap = t >> 9;
        int o  = mtg * 16 + (L & 15);
        int cb = kc * 32 + (L >> 4) * 8;
        bf16x8 vv;
        #pragma unroll
        for (int j = 0; j < 8; j++)
            vv[j] = (bf16)wgt[(o * 64 + (cb + j)) * 9 + tap];
        *(bf16x8*)(wpk + t * 8) = vv;
    }
    int z = t - 9 * 2 * 4 * 64;
    if (z >= 0 && z < 2304) accums[z] = 0.0f;   // dots(2048)+qss(128)+kss(128)
}

// ---------------- K1: 3x3 conv, staging straight from f32 clone ------------
// block: 256 thr = 4 waves; tile = 64 out-ch x 6 rows x 64 cols.
// grid = 5 x 43 x 2 = 430 blocks, 2 blocks/CU -> single occupancy round.
// dynamic LDS = 8*68*72*2 = 78336 B.
__global__ __launch_bounds__(256, 2) void k1_conv(const float* __restrict__ clone,
                                                  const bf16* __restrict__ wpk,
                                                  bf16* __restrict__ cext) {
    const int Xt = blockIdx.x;   // 0..4
    const int Yt = blockIdx.y;   // 0..42  (43*6 = 258 exactly)
    const int b  = blockIdx.z;
    const int t  = threadIdx.x;
    const int L  = t & 63;
    const int wv = t >> 6;
    const int mpair = wv >> 1;
    const int npair = wv & 1;

    extern __shared__ bf16 tile[];       // [8 rows][68 cols][c pitch 72]

    // preload weight A-fragments: [mt][tap][kc]
    bf16x8 afrag[2][9][2];
    #pragma unroll
    for (int mt = 0; mt < 2; mt++)
        #pragma unroll
        for (int tap = 0; tap < 9; tap++)
            #pragma unroll
            for (int kc = 0; kc < 2; kc++) {
                int idx = ((tap * 2 + kc) * 4 + (mpair * 2 + mt)) * 64 + L;
                afrag[mt][tap][kc] = *(const bf16x8*)(wpk + idx * 8);
            }

    // stage: rows Yt*6-2..+5 (8), x = Xt*64-4..+63 (68 cols, 4-aligned), 64 ch.
    // unit = (r, cg[4ch], xq[4col]): 4 coalesced f32x4 loads -> in-register
    // 4x4 transpose -> 4 ds_write_b64 at [r][col][c0].
    for (int u = t; u < 2176; u += 256) {
        int xq = u % 17;
        int rc = u / 17;
        int cg = rc & 15;
        int r  = rc >> 4;
        int y  = Yt * 6 - 2 + r;
        int xg0 = Xt * 64 - 4 + xq * 4;
        int c0 = cg * 4;
        f32x4 f[4];
        bool yin = (y >= 0) && (y < HH);
        if (yin && xg0 >= 0 && xg0 + 3 < WW) {
            #pragma unroll
            for (int i = 0; i < 4; i++)
                f[i] = *(const f32x4*)(clone + ((size_t)(b * NC + c0 + i) * HH + y) * WW + xg0);
        } else {
            #pragma unroll
            for (int i = 0; i < 4; i++)
                #pragma unroll
                for (int e = 0; e < 4; e++) {
                    int xg = xg0 + e;
                    f[i][e] = (yin && xg >= 0 && xg < WW)
                            ? clone[((size_t)(b * NC + c0 + i) * HH + y) * WW + xg] : 0.0f;
                }
        }
        #pragma unroll
        for (int e = 0; e < 4; e++) {
            bf16x4 h;
            #pragma unroll
            for (int i = 0; i < 4; i++) h[i] = (bf16)f[i][e];
            *(bf16x4*)(tile + (r * 68 + xq * 4 + e) * 72 + c0) = h;
        }
    }
    __syncthreads();

    const f32x4 zero4 = {0.0f, 0.0f, 0.0f, 0.0f};
    for (int Yi = 0; Yi < 6; Yi++) {
        f32x4 acc[2][2];
        acc[0][0] = zero4; acc[0][1] = zero4; acc[1][0] = zero4; acc[1][1] = zero4;
        #pragma unroll
        for (int tap = 0; tap < 9; tap++) {
            const int ky = tap / 3 - 1;
            const int kx = tap % 3 - 1;
            const int r = Yi + 1 + ky;
            #pragma unroll
            for (int kc = 0; kc < 2; kc++) {
                const int cb = kc * 32 + (L >> 4) * 8;
                #pragma unroll
                for (int nt = 0; nt < 2; nt++) {
                    // col: tile col 0 <-> xg = Xt*64-4, output pos p <-> col p+4;
                    // sample x = p + kx -> col = p + kx + 4... p = npair*32+nt*16+(L&15)
                    const int col = npair * 32 + nt * 16 + (L & 15) + kx + 3;
                    bf16x8 bfrag = *(const bf16x8*)(tile + (r * 68 + col) * 72 + cb);
                    #pragma unroll
                    for (int mt = 0; mt < 2; mt++)
                        acc[mt][nt] = __builtin_amdgcn_mfma_f32_16x16x32_bf16(
                            afrag[mt][tap][kc], bfrag, acc[mt][nt], 0, 0, 0);
                }
            }
        }
        int Yp = Yt * 6 + Yi;    // always < 258
        #pragma unroll
        for (int mt = 0; mt < 2; mt++)
            #pragma unroll
            for (int nt = 0; nt < 2; nt++) {
                int Xp = Xt * 64 + npair * 32 + nt * 16 + (L & 15);
                if (Xp < EX) {
                    int o = mpair * 32 + mt * 16 + (L >> 4) * 4;
                    bf16x4 st;
                    #pragma unroll
                    for (int rg = 0; rg < 4; rg++) st[rg] = (bf16)acc[mt][nt][rg];
                    // cext is [b][Yp][Xp][o] bf16
                    *(bf16x4*)(cext + ((((size_t)b * EX + Yp) * EX + Xp) << 6) + o) = st;
                }
            }
    }
}

// NOTE on tile col mapping: output position p (0..63) sits at global x = Xt*64+p,
// which is tile col p+4 (tile col 0 = Xt*64-4). Sampling x+kx -> col p+kx+4.
// MFMA uses col = p + kx + 3?? -> p index here includes the +1 from the old
// layout; verified: old col = p+kx+1 with origin Xt*64-2; new origin is 2 cols
// earlier -> +2 -> p+kx+3. (p_min=0,kx=-1 -> col 2 = x=Xt*64-2 OK)

// ---------------- K23: bilinear gather -> kv, then fused dots (L2-hot) -----
__global__ __launch_bounds__(256) void k23(const float* __restrict__ uu,
                                           const float* __restrict__ vv,
                                           const bf16* __restrict__ cext,
                                           const float* __restrict__ x,
                                           bf16* __restrict__ kv,
                                           float* __restrict__ dots,
                                           float* __restrict__ qss,
                                           float* __restrict__ kss) {
    const int ci = blockIdx.x;   // 0..255: 256-pixel chunk
    const int b  = blockIdx.y;
    const int t  = threadIdx.x;

    // ---- phase A: gather 256 pixels x 64 ch (2 units/thread) ----
    #pragma unroll
    for (int it2 = 0; it2 < 2; it2++) {
        int unit = it2 * 256 + t;
        int ckh = unit >> 8;                    // channel half
        int pix = unit & 255;
        int hw = ci * 256 + pix;
        int idx = b * NS + hw;
        int hy = hw >> 8;
        int wx = hw & 255;
        float fv = vv[idx];
        float fu = uu[idx];
        float py = (float)hy + fv;
        float px = (float)wx + fu;
        float fy = floorf(py);
        float fx = floorf(px);
        float ay = py - fy;
        float ax = px - fx;
        int ys = (int)fy + 1;    // storage coords on EX grid
        int xs = (int)fx + 1;
        float w00 = (1.0f - ay) * (1.0f - ax);
        float w01 = (1.0f - ay) * ax;
        float w10 = ay * (1.0f - ax);
        float w11 = ay * ax;
        bool y0i = (ys >= 0) && (ys < EX);
        bool y1i = (ys + 1 >= 0) && (ys + 1 < EX);
        bool x0i = (xs >= 0) && (xs < EX);
        bool x1i = (xs + 1 >= 0) && (xs + 1 < EX);
        if (!y0i) { w00 = 0.0f; w01 = 0.0f; }
        if (!y1i) { w10 = 0.0f; w11 = 0.0f; }
        if (!x0i) { w00 = 0.0f; w10 = 0.0f; }
        if (!x1i) { w01 = 0.0f; w11 = 0.0f; }
        int y0c = ys < 0 ? 0 : (ys > EX - 1 ? EX - 1 : ys);
        int y1c = ys + 1 < 0 ? 0 : (ys + 1 > EX - 1 ? EX - 1 : ys + 1);
        int x0c = xs < 0 ? 0 : (xs > EX - 1 ? EX - 1 : xs);
        int x1c = xs + 1 < 0 ? 0 : (xs + 1 > EX - 1 ? EX - 1 : xs + 1);
        const bf16* pb = cext + (((size_t)b * EX * EX) << 6);
        size_t i00 = ((size_t)(y0c * EX + x0c)) << 6;
        size_t i01 = ((size_t)(y0c * EX + x1c)) << 6;
        size_t i10 = ((size_t)(y1c * EX + x0c)) << 6;
        size_t i11 = ((size_t)(y1c * EX + x1c)) << 6;
        bf16* kvp = kv + (((size_t)(b * NC + ckh * 32)) << 16) + hw;
        #pragma unroll
        for (int ck = 0; ck < 4; ck++) {
            int c0 = ckh * 32 + ck * 8;
            bf16x8 c00 = *(const bf16x8*)(pb + i00 + c0);
            bf16x8 c01 = *(const bf16x8*)(pb + i01 + c0);
            bf16x8 c10 = *(const bf16x8*)(pb + i10 + c0);
            bf16x8 c11 = *(const bf16x8*)(pb + i11 + c0);
            #pragma unroll
            for (int j = 0; j < 8; j++) {
                float val = w00 * (float)c00[j] + w01 * (float)c01[j]
                          + w10 * (float)c10[j] + w11 * (float)c11[j];
                kvp[((size_t)(ck * 8 + j)) << 16] = (bf16)val;
            }
        }
    }
    __syncthreads();   // drains stores -> kv visible in this CU's L2

    // ---- phase B: per-wave head dots over this 256-s chunk ----
    const int L = t & 63;
    const int w = t >> 6;        // wave = head
    const int row = L & 15;
    const int kg  = L >> 4;
    const float* qb = x  + ((size_t)(b * NC + w * DH + row)) * NS;
    const bf16*  kb = kv + (((size_t)(b * NC + w * DH + row)) << 16);
    f32x4 acc = {0.0f, 0.0f, 0.0f, 0.0f};
    float qp = 0.0f, kp = 0.0f;
    const int s0 = ci * 256 + kg * 8;
    for (int iter = 0; iter < 8; iter++) {
        int s = s0 + iter * 32;
        f32x4 q0 = *(const f32x4*)(qb + s);
        f32x4 q1 = *(const f32x4*)(qb + s + 4);
        bf16x8 ka = *(const bf16x8*)(kb + s);
        bf16x8 qa;
        #pragma unroll
        for (int j = 0; j < 4; j++) {
            qa[j]     = (bf16)q0[j];
            qa[j + 4] = (bf16)q1[j];
        }
        qp += q0[0]*q0[0] + q0[1]*q0[1] + q0[2]*q0[2] + q0[3]*q0[3]
            + q1[0]*q1[0] + q1[1]*q1[1] + q1[2]*q1[2] + q1[3]*q1[3];
        #pragma unroll
        for (int j = 0; j < 8; j++) {
            float kf = (float)ka[j];
            kp += kf * kf;
        }
        acc = __builtin_amdgcn_mfma_f32_16x16x32_bf16(qa, ka, acc, 0, 0, 0);
    }
    __shared__ float ldsD[1024];
    __shared__ float ldsQ[64];
    __shared__ float ldsK[64];
    #pragma unroll
    for (int w2 = 0; w2 < 4; w2++) ldsD[w2 * 256 + t] = 0.0f;
    if (t < 64) { ldsQ[t] = 0.0f; ldsK[t] = 0.0f; }
    __syncthreads();
    #pragma unroll
    for (int rg = 0; rg < 4; rg++)
        atomicAdd(&ldsD[w * 256 + (kg * 4 + rg) * 16 + row], acc[rg]);
    atomicAdd(&ldsQ[w * 16 + row], qp);
    atomicAdd(&ldsK[w * 16 + row], kp);
    __syncthreads();
    #pragma unroll
    for (int w2 = 0; w2 < 4; w2++)
        atomicAdd(&dots[(b * NHEAD + w2) * 256 + t], ldsD[w2 * 256 + t]);
    if (t < 64) {
        atomicAdd(&qss[b * 64 + t], ldsQ[t]);
        atomicAdd(&kss[b * 64 + t], ldsK[t]);
    }
}

// ---------------- K5: softmax (redundant per block) + out = attn @ kv ------
__global__ __launch_bounds__(256) void k5_out(const bf16* __restrict__ kv,
                                              const float* __restrict__ dots,
                                              const float* __restrict__ qss,
                                              const float* __restrict__ kss,
                                              const float* __restrict__ temp,
                                              float* __restrict__ out) {
    const int ci = blockIdx.x;  // 0..63 (1024 s per block)
    const int h  = blockIdx.y;
    const int b  = blockIdx.z;
    const int t  = threadIdx.x;
    const int bh = b * NHEAD + h;
    __shared__ float l[256];
    __shared__ float a[256];
    {
        int i = t >> 4, j = t & 15;
        float qn = fmaxf(sqrtf(qss[bh * 16 + i]), 1e-12f);
        float kn = fmaxf(sqrtf(kss[bh * 16 + j]), 1e-12f);
        float logit = dots[bh * 256 + t] / (qn * kn) * temp[h];
        l[t] = logit;
        __syncthreads();
        float mx = -1e30f;
        #pragma unroll
        for (int jj = 0; jj < 16; jj++) mx = fmaxf(mx, l[i * 16 + jj]);
        float sum = 0.0f;
        #pragma unroll
        for (int jj = 0; jj < 16; jj++) sum += expf(l[i * 16 + jj] - mx);
        a[t] = expf(logit - mx) / sum;
        __syncthreads();
    }
    const int s = (ci * 256 + t) * 4;
    const bf16* kvb = kv + (((size_t)(b * NC + h * DH)) << 16) + s;
    f32x4 kf[16];
    #pragma unroll
    for (int j = 0; j < 16; j++) {
        bf16x4 kk = *(const bf16x4*)(kvb + ((size_t)j << 16));
        #pragma unroll
        for (int e = 0; e < 4; e++) kf[j][e] = (float)kk[e];
    }
    float* ob = out + ((size_t)(b * NC + h * DH)) * NS + s;
    #pragma unroll
    for (int i = 0; i < 16; i++) {
        f32x4 o = {0.0f, 0.0f, 0.0f, 0.0f};
        #pragma unroll
        for (int j = 0; j < 16; j++)
            o += a[i * 16 + j] * kf[j];
        *(f32x4*)(ob + (size_t)i * NS) = o;
    }
}

extern "C" void kernel_launch(void* const* d_in, const int* in_sizes, int n_in,
                              void* d_out, int out_size, void* d_ws, size_t ws_size,
                              hipStream_t stream) {
    const float* clone = (const float*)d_in[0];
    const float* x     = (const float*)d_in[1];
    const float* u     = (const float*)d_in[2];
    const float* v     = (const float*)d_in[3];
    const float* wgt   = (const float*)d_in[4];
    const float* temp  = (const float*)d_in[5];
    float* out = (float*)d_out;

    char* ws = (char*)d_ws;
    bf16*  cext   = (bf16*) (ws + OFF_CEXT);
    bf16*  kv     = (bf16*) (ws + OFF_KV);
    bf16*  wpk    = (bf16*) (ws + OFF_WPK);
    float* accums = (float*)(ws + OFF_ACC);
    float* dots = accums;
    float* qss  = accums + 2048;
    float* kss  = accums + 2048 + 128;

    static bool attr_set = false;
    if (!attr_set) {
        hipFuncSetAttribute((const void*)k1_conv,
                            hipFuncAttributeMaxDynamicSharedMemorySize, 78336);
        attr_set = true;
    }

    k0w<<<27, 256, 0, stream>>>(wgt, wpk, accums);
    k1_conv<<<dim3(5, 43, 2), 256, 78336, stream>>>(clone, wpk, cext);
    k23<<<dim3(256, 2), 256, 0, stream>>>(u, v, cext, x, kv, dots, qss, kss);
    k5_out<<<dim3(64, 4, 2), 256, 0, stream>>>(kv, dots, qss, kss, temp, out);
}

// Round 5
// 161.903 us; speedup vs baseline: 1.5510x; 1.0657x over previous
//
#include <hip/hip_runtime.h>

typedef __bf16 bf16;
typedef __bf16 bf16x4 __attribute__((ext_vector_type(4)));
typedef __bf16 bf16x8 __attribute__((ext_vector_type(8)));
typedef float  f32x4  __attribute__((ext_vector_type(4)));

#define HH 256
#define WW 256
#define NB 2
#define NC 64
#define NS 65536
#define EX 258      // extended conv grid: real coords -1..256, stored +1
#define NHEAD 4
#define DH 16

// ws layout (bytes)
#define OFF_CEXT   0ul                 // 2*258*258*64*2 = 17040384
#define OFF_KV     17040384ul          // 2*64*65536*2   = 16777216
#define OFF_WPK    33817600ul          // 73728
#define OFF_ACC    33891328ul          // 9216

// ---------------- K0w: pack weights to A-frag layout + zero accums ---------
__global__ void k0w(const float* __restrict__ wgt, bf16* __restrict__ wpk,
                    float* __restrict__ accums) {
    int t = blockIdx.x * 256 + threadIdx.x;
    if (t < 9 * 2 * 4 * 64) {
        int L   = t & 63;
        int mtg = (t >> 6) & 3;
        int kc  = (t >> 8) & 1;
        int tap = t >> 9;
        int o  = mtg * 16 + (L & 15);
        int cb = kc * 32 + (L >> 4) * 8;
        bf16x8 vv;
        #pragma unroll
        for (int j = 0; j < 8; j++)
            vv[j] = (bf16)wgt[(o * 64 + (cb + j)) * 9 + tap];
        *(bf16x8*)(wpk + t * 8) = vv;
    }
    int z = t - 9 * 2 * 4 * 64;
    if (z >= 0 && z < 2304) accums[z] = 0.0f;   // dots(2048)+qss(128)+kss(128)
}

// ---------------- K1: 3x3 conv, staging straight from f32 clone ------------
// block: 256 thr = 4 waves; tile = 64 out-ch x 6 rows x 64 cols.
// grid = 5 x 43 x 2 = 430 blocks, 2 blocks/CU -> single occupancy round.
// dynamic LDS = 8*68*72*2 = 78336 B.
__global__ __launch_bounds__(256, 2) void k1_conv(const float* __restrict__ clone,
                                                  const bf16* __restrict__ wpk,
                                                  bf16* __restrict__ cext) {
    const int Xt = blockIdx.x;   // 0..4
    const int Yt = blockIdx.y;   // 0..42  (43*6 = 258 exactly)
    const int b  = blockIdx.z;
    const int t  = threadIdx.x;
    const int L  = t & 63;
    const int wv = t >> 6;
    const int mpair = wv >> 1;
    const int npair = wv & 1;

    extern __shared__ bf16 tile[];       // [8 rows][68 cols][c pitch 72]

    // preload weight A-fragments: [mt][tap][kc]
    bf16x8 afrag[2][9][2];
    #pragma unroll
    for (int mt = 0; mt < 2; mt++)
        #pragma unroll
        for (int tap = 0; tap < 9; tap++)
            #pragma unroll
            for (int kc = 0; kc < 2; kc++) {
                int idx = ((tap * 2 + kc) * 4 + (mpair * 2 + mt)) * 64 + L;
                afrag[mt][tap][kc] = *(const bf16x8*)(wpk + idx * 8);
            }

    // stage: rows Yt*6-2..+5 (8), x = Xt*64-4..+63 (68 cols, 4-aligned), 64 ch.
    for (int u = t; u < 2176; u += 256) {
        int xq = u % 17;
        int rc = u / 17;
        int cg = rc & 15;
        int r  = rc >> 4;
        int y  = Yt * 6 - 2 + r;
        int xg0 = Xt * 64 - 4 + xq * 4;
        int c0 = cg * 4;
        f32x4 f[4];
        bool yin = (y >= 0) && (y < HH);
        if (yin && xg0 >= 0 && xg0 + 3 < WW) {
            #pragma unroll
            for (int i = 0; i < 4; i++)
                f[i] = *(const f32x4*)(clone + ((size_t)(b * NC + c0 + i) * HH + y) * WW + xg0);
        } else {
            #pragma unroll
            for (int i = 0; i < 4; i++)
                #pragma unroll
                for (int e = 0; e < 4; e++) {
                    int xg = xg0 + e;
                    f[i][e] = (yin && xg >= 0 && xg < WW)
                            ? clone[((size_t)(b * NC + c0 + i) * HH + y) * WW + xg] : 0.0f;
                }
        }
        #pragma unroll
        for (int e = 0; e < 4; e++) {
            bf16x4 h;
            #pragma unroll
            for (int i = 0; i < 4; i++) h[i] = (bf16)f[i][e];
            *(bf16x4*)(tile + (r * 68 + xq * 4 + e) * 72 + c0) = h;
        }
    }
    __syncthreads();

    const f32x4 zero4 = {0.0f, 0.0f, 0.0f, 0.0f};
    for (int Yi = 0; Yi < 6; Yi++) {
        f32x4 acc[2][2];
        acc[0][0] = zero4; acc[0][1] = zero4; acc[1][0] = zero4; acc[1][1] = zero4;
        #pragma unroll
        for (int tap = 0; tap < 9; tap++) {
            const int ky = tap / 3 - 1;
            const int kx = tap % 3 - 1;
            const int r = Yi + 1 + ky;
            #pragma unroll
            for (int kc = 0; kc < 2; kc++) {
                const int cb = kc * 32 + (L >> 4) * 8;
                #pragma unroll
                for (int nt = 0; nt < 2; nt++) {
                    // output pos p at tile col p+4 (col 0 = Xt*64-4); sample p+kx -> col p+kx+3 (+1 pos offset)
                    const int col = npair * 32 + nt * 16 + (L & 15) + kx + 3;
                    bf16x8 bfrag = *(const bf16x8*)(tile + (r * 68 + col) * 72 + cb);
                    #pragma unroll
                    for (int mt = 0; mt < 2; mt++)
                        acc[mt][nt] = __builtin_amdgcn_mfma_f32_16x16x32_bf16(
                            afrag[mt][tap][kc], bfrag, acc[mt][nt], 0, 0, 0);
                }
            }
        }
        int Yp = Yt * 6 + Yi;    // always < 258
        #pragma unroll
        for (int mt = 0; mt < 2; mt++)
            #pragma unroll
            for (int nt = 0; nt < 2; nt++) {
                int Xp = Xt * 64 + npair * 32 + nt * 16 + (L & 15);
                if (Xp < EX) {
                    int o = mpair * 32 + mt * 16 + (L >> 4) * 4;
                    bf16x4 st;
                    #pragma unroll
                    for (int rg = 0; rg < 4; rg++) st[rg] = (bf16)acc[mt][nt][rg];
                    // cext is [b][Yp][Xp][o] bf16
                    *(bf16x4*)(cext + ((((size_t)b * EX + Yp) * EX + Xp) << 6) + o) = st;
                }
            }
    }
}

// ---------------- K2: 4-corner bilinear gather, 32x8 pixel tiles -----------
// thread = 1 pixel, all 64 ch (32 independent 16B loads -> high MLP).
// 2D tiling cuts cext y-overfetch from ~4x to ~1.75x.
__global__ __launch_bounds__(256) void k2_gather(const float* __restrict__ uu,
                                                 const float* __restrict__ vv,
                                                 const bf16* __restrict__ cext,
                                                 bf16* __restrict__ kv) {
    const int tx = blockIdx.x;   // 0..7   (32-px col tile)
    const int ty = blockIdx.y;   // 0..31  (8-row tile)
    const int b  = blockIdx.z;
    const int t  = threadIdx.x;
    const int px = t & 31, py = t >> 5;
    const int hw = (ty * 8 + py) * 256 + tx * 32 + px;
    const int idx = b * NS + hw;
    const int hy = hw >> 8;
    const int wx = hw & 255;
    float fv = vv[idx];
    float fu = uu[idx];
    float py_f = (float)hy + fv;
    float px_f = (float)wx + fu;
    float fy = floorf(py_f);
    float fx = floorf(px_f);
    float ay = py_f - fy;
    float ax = px_f - fx;
    int ys = (int)fy + 1;    // storage coords on EX grid
    int xs = (int)fx + 1;
    float w00 = (1.0f - ay) * (1.0f - ax);
    float w01 = (1.0f - ay) * ax;
    float w10 = ay * (1.0f - ax);
    float w11 = ay * ax;
    bool y0i = (ys >= 0) && (ys < EX);
    bool y1i = (ys + 1 >= 0) && (ys + 1 < EX);
    bool x0i = (xs >= 0) && (xs < EX);
    bool x1i = (xs + 1 >= 0) && (xs + 1 < EX);
    if (!y0i) { w00 = 0.0f; w01 = 0.0f; }
    if (!y1i) { w10 = 0.0f; w11 = 0.0f; }
    if (!x0i) { w00 = 0.0f; w10 = 0.0f; }
    if (!x1i) { w01 = 0.0f; w11 = 0.0f; }
    int y0c = ys < 0 ? 0 : (ys > EX - 1 ? EX - 1 : ys);
    int y1c = ys + 1 < 0 ? 0 : (ys + 1 > EX - 1 ? EX - 1 : ys + 1);
    int x0c = xs < 0 ? 0 : (xs > EX - 1 ? EX - 1 : xs);
    int x1c = xs + 1 < 0 ? 0 : (xs + 1 > EX - 1 ? EX - 1 : xs + 1);
    const bf16* pb = cext + (((size_t)b * EX * EX) << 6);
    size_t i00 = ((size_t)(y0c * EX + x0c)) << 6;
    size_t i01 = ((size_t)(y0c * EX + x1c)) << 6;
    size_t i10 = ((size_t)(y1c * EX + x0c)) << 6;
    size_t i11 = ((size_t)(y1c * EX + x1c)) << 6;
    bf16* kvp = kv + (((size_t)(b * NC)) << 16) + hw;
    #pragma unroll
    for (int ck = 0; ck < 8; ck++) {
        int c0 = ck * 8;
        bf16x8 c00 = *(const bf16x8*)(pb + i00 + c0);
        bf16x8 c01 = *(const bf16x8*)(pb + i01 + c0);
        bf16x8 c10 = *(const bf16x8*)(pb + i10 + c0);
        bf16x8 c11 = *(const bf16x8*)(pb + i11 + c0);
        #pragma unroll
        for (int j = 0; j < 8; j++) {
            float val = w00 * (float)c00[j] + w01 * (float)c01[j]
                      + w10 * (float)c10[j] + w11 * (float)c11[j];
            kvp[((size_t)(c0 + j)) << 16] = (bf16)val;
        }
    }
}

// ---------------- K3: fused q.kT dots + sumsq norms via MFMA ---------------
// 512-px chunks -> grid 128x4x2 = 1024 blocks (4/CU).
__global__ __launch_bounds__(256) void k3_dots(const float* __restrict__ x,
                                               const bf16* __restrict__ kv,
                                               float* __restrict__ dots,
                                               float* __restrict__ qss,
                                               float* __restrict__ kss) {
    const int ch = blockIdx.x;   // 0..127 chunks of 512 along S
    const int h  = blockIdx.y;
    const int b  = blockIdx.z;
    const int t  = threadIdx.x;
    const int L  = t & 63;
    const int wv = t >> 6;
    const int row = L & 15;
    const int kg  = L >> 4;
    const float* qb = x + ((size_t)(b * NC + h * DH + row)) * NS;
    const bf16*  kb = kv + (((size_t)(b * NC + h * DH + row)) << 16);
    f32x4 acc = {0.0f, 0.0f, 0.0f, 0.0f};
    float qp = 0.0f, kp = 0.0f;
    const int s0 = ch * 512 + wv * 128 + kg * 8;
    #pragma unroll
    for (int it = 0; it < 4; it++) {
        int s = s0 + it * 32;
        f32x4 q0 = *(const f32x4*)(qb + s);
        f32x4 q1 = *(const f32x4*)(qb + s + 4);
        bf16x8 ka = *(const bf16x8*)(kb + s);
        bf16x8 qa;
        #pragma unroll
        for (int j = 0; j < 4; j++) {
            qa[j]     = (bf16)q0[j];
            qa[j + 4] = (bf16)q1[j];
        }
        qp += q0[0]*q0[0] + q0[1]*q0[1] + q0[2]*q0[2] + q0[3]*q0[3]
            + q1[0]*q1[0] + q1[1]*q1[1] + q1[2]*q1[2] + q1[3]*q1[3];
        #pragma unroll
        for (int j = 0; j < 8; j++) {
            float kf = (float)ka[j];
            kp += kf * kf;
        }
        acc = __builtin_amdgcn_mfma_f32_16x16x32_bf16(qa, ka, acc, 0, 0, 0);
    }
    __shared__ float ldsD[256];
    __shared__ float ldsQ[16];
    __shared__ float ldsK[16];
    ldsD[t] = 0.0f;
    if (t < 16) { ldsQ[t] = 0.0f; ldsK[t] = 0.0f; }
    __syncthreads();
    #pragma unroll
    for (int rg = 0; rg < 4; rg++)
        atomicAdd(&ldsD[(kg * 4 + rg) * 16 + row], acc[rg]);
    atomicAdd(&ldsQ[row], qp);
    atomicAdd(&ldsK[row], kp);
    __syncthreads();
    const int bh = b * NHEAD + h;
    atomicAdd(&dots[bh * 256 + t], ldsD[t]);
    if (t < 16) {
        atomicAdd(&qss[bh * 16 + t], ldsQ[t]);
        atomicAdd(&kss[bh * 16 + t], ldsK[t]);
    }
}

// ---------------- K5: softmax (redundant per block) + out = attn @ kv ------
__global__ __launch_bounds__(256) void k5_out(const bf16* __restrict__ kv,
                                              const float* __restrict__ dots,
                                              const float* __restrict__ qss,
                                              const float* __restrict__ kss,
                                              const float* __restrict__ temp,
                                              float* __restrict__ out) {
    const int ci = blockIdx.x;  // 0..63 (1024 s per block)
    const int h  = blockIdx.y;
    const int b  = blockIdx.z;
    const int t  = threadIdx.x;
    const int bh = b * NHEAD + h;
    __shared__ float l[256];
    __shared__ float a[256];
    {
        int i = t >> 4, j = t & 15;
        float qn = fmaxf(sqrtf(qss[bh * 16 + i]), 1e-12f);
        float kn = fmaxf(sqrtf(kss[bh * 16 + j]), 1e-12f);
        float logit = dots[bh * 256 + t] / (qn * kn) * temp[h];
        l[t] = logit;
        __syncthreads();
        float mx = -1e30f;
        #pragma unroll
        for (int jj = 0; jj < 16; jj++) mx = fmaxf(mx, l[i * 16 + jj]);
        float sum = 0.0f;
        #pragma unroll
        for (int jj = 0; jj < 16; jj++) sum += expf(l[i * 16 + jj] - mx);
        a[t] = expf(logit - mx) / sum;
        __syncthreads();
    }
    const int s = (ci * 256 + t) * 4;
    const bf16* kvb = kv + (((size_t)(b * NC + h * DH)) << 16) + s;
    f32x4 kf[16];
    #pragma unroll
    for (int j = 0; j < 16; j++) {
        bf16x4 kk = *(const bf16x4*)(kvb + ((size_t)j << 16));
        #pragma unroll
        for (int e = 0; e < 4; e++) kf[j][e] = (float)kk[e];
    }
    float* ob = out + ((size_t)(b * NC + h * DH)) * NS + s;
    #pragma unroll
    for (int i = 0; i < 16; i++) {
        f32x4 o = {0.0f, 0.0f, 0.0f, 0.0f};
        #pragma unroll
        for (int j = 0; j < 16; j++)
            o += a[i * 16 + j] * kf[j];
        *(f32x4*)(ob + (size_t)i * NS) = o;
    }
}

extern "C" void kernel_launch(void* const* d_in, const int* in_sizes, int n_in,
                              void* d_out, int out_size, void* d_ws, size_t ws_size,
                              hipStream_t stream) {
    const float* clone = (const float*)d_in[0];
    const float* x     = (const float*)d_in[1];
    const float* u     = (const float*)d_in[2];
    const float* v     = (const float*)d_in[3];
    const float* wgt   = (const float*)d_in[4];
    const float* temp  = (const float*)d_in[5];
    float* out = (float*)d_out;

    char* ws = (char*)d_ws;
    bf16*  cext   = (bf16*) (ws + OFF_CEXT);
    bf16*  kv     = (bf16*) (ws + OFF_KV);
    bf16*  wpk    = (bf16*) (ws + OFF_WPK);
    float* accums = (float*)(ws + OFF_ACC);
    float* dots = accums;
    float* qss  = accums + 2048;
    float* kss  = accums + 2048 + 128;

    static bool attr_set = false;
    if (!attr_set) {
        hipFuncSetAttribute((const void*)k1_conv,
                            hipFuncAttributeMaxDynamicSharedMemorySize, 78336);
        attr_set = true;
    }

    k0w<<<27, 256, 0, stream>>>(wgt, wpk, accums);
    k1_conv<<<dim3(5, 43, 2), 256, 78336, stream>>>(clone, wpk, cext);
    k2_gather<<<dim3(8, 32, 2), 256, 0, stream>>>(u, v, cext, kv);
    k3_dots<<<dim3(128, 4, 2), 256, 0, stream>>>(x, kv, dots, qss, kss);
    k5_out<<<dim3(64, 4, 2), 256, 0, stream>>>(kv, dots, qss, kss, temp, out);
}